// Round 12
// baseline (161.815 us; speedup 1.0000x reference)
//
#include <hip/hip_runtime.h>
#include <hip/hip_bf16.h>
#include <hip/hip_cooperative_groups.h>
#include <math.h>

#define BB 4
#define CC 256
#define HH 128
#define WW 128
#define NN (HH*WW)
#define DD 32

// AOT: attention output, bf16, spatially padded +1 border, ci padded 32->44.
#define AOT_CI   44
#define AOT_ROWE (130*AOT_CI)                  // shorts per padded row (5720)
#define AOT_IMGE (130*AOT_ROWE)                // shorts per batch (743600)
#define AOT_BYTES ((size_t)BB*AOT_IMGE*2)      // 5,948,800
#define AOT_ALLOC (AOT_BYTES + 1024)

#define WT_BYTES (9*256*AOT_CI*2)              // 202,752

// conv LDS geometry (2-row tile)
#define PATCH_SZ 45760                         // 4 padded rows * 130 * 88
#define WSLAB    22528                         // 256 co * 88
#define CONV_LDS (PATCH_SZ + 2*WSLAB)          // 90,816
#define EPI_PITCH 260

// fused qkv+attn: A image [16 kstep][hi/lo][3 cf][64 lane][16B] = 96 KB
#define ASWZ_BYTES 98304
#define QKVP 260                               // qk epilogue tile pitch (floats)
// LDS map: A/qk 0..98303 | stage bufs 98304,114688 (16KB ea) | bias 131072
// phase2 at4 reuses 98304 (32 rows x 36 pitch floats)
#define QKV_LDS 131584

typedef __attribute__((ext_vector_type(8)))  short bf16x8;
typedef __attribute__((ext_vector_type(4)))  float f32x4;
typedef __attribute__((ext_vector_type(16))) float f32x16;

namespace cg = cooperative_groups;

__device__ inline void async_copy16(void* lds, const void* g) {
    __builtin_amdgcn_global_load_lds(
        (const __attribute__((address_space(1))) unsigned int*)g,
        (__attribute__((address_space(3))) unsigned int*)lds, 16, 0, 0);
}

__device__ inline unsigned short f2bf(float f) {
    __hip_bfloat16 h = __float2bfloat16(f);
    return *reinterpret_cast<unsigned short*>(&h);
}

__device__ inline void split2(float v, unsigned short& h, unsigned short& l) {
    __hip_bfloat16 hb = __float2bfloat16(v);
    float r = v - __bfloat162float(hb);     // exact (Sterbenz)
    __hip_bfloat16 lb = __float2bfloat16(r);
    h = *reinterpret_cast<unsigned short*>(&hb);
    l = *reinterpret_cast<unsigned short*>(&lb);
}

// truncation split packed: low16 = bf16(hi), high16 = bf16(lo residual)
__device__ inline unsigned int packsplit(float v) {
    unsigned int fb = __float_as_uint(v);
    unsigned int hb = fb & 0xFFFF0000u;
    float r = v - __uint_as_float(hb);
    unsigned int lb = __float_as_uint(r) >> 16;
    return (hb >> 16) | (lb << 16);
}

// 8B+8B LDS load of a bf16x8 fragment (88B row pitch is only 8B-aligned)
__device__ inline bf16x8 ld_frag8(const char* p) {
    union { bf16x8 v; short4 h[2]; } u;
    u.h[0] = *(const short4*)(p);
    u.h[1] = *(const short4*)(p + 8);
    return u.v;
}

// A&S 7.1.26 erf approximation, |err| ~1e-6
__device__ inline float gelu_fast(float v) {
    float a = fabsf(v) * 0.70710678118654752f;
    float t = __fdividef(1.0f, fmaf(0.3275911f, a, 1.0f));
    float p = t * fmaf(t, fmaf(t, fmaf(t, fmaf(t, 1.061405429f, -1.453152027f),
                                       1.421413741f), -0.284496736f), 0.254829592f);
    float e = 1.0f - p * __expf(-a * a);
    float erfv = (v < 0.0f) ? -e : e;
    return 0.5f * v * (1.0f + erfv);
}

// ---------------------------------------------------------------------------
// K0: fused prep — conv weight repack | qkv A-pack | AOT border zero.
// ---------------------------------------------------------------------------
__global__ __launch_bounds__(256) void prep_kernel(
    const float* __restrict__ wp, unsigned short* __restrict__ Wt,
    const float* __restrict__ wq, const float* __restrict__ wk,
    const float* __restrict__ wv, unsigned short* __restrict__ Aswz,
    unsigned short* __restrict__ AOT)
{
    const int blk = blockIdx.x;
    if (blk < 288) {                       // conv weights: 9*256*32 = 73728
        int i = blk*256 + threadIdx.x;
        int kk = i / (256*32);
        int r  = i % (256*32);
        int co = r >> 5, ci = r & 31;
        float v = wp[((size_t)co*32 + ci)*9 + kk];
        Wt[((size_t)kk*256 + co)*AOT_CI + ci] = f2bf(v);
    } else if (blk < 480) {                // qkv A image: 49152 entries
        int i = (blk-288)*256 + threadIdx.x;
        int j    = i & 7;
        int lane = (i >> 3) & 63;
        int q9   = i >> 9;                 // (s*2+hl)*3 + cf, 0..95
        int cf   = q9 % 3;
        int t    = q9 / 3;
        int hl   = t & 1;
        int s    = t >> 1;                 // 0..15
        int row  = cf*32 + (lane & 31);
        int c    = s*16 + (lane >> 5)*8 + j;
        float w  = (row < 32) ? wq[row*256 + c]
                 : (row < 64) ? wk[(row-32)*256 + c]
                              : wv[(row-64)*256 + c];
        unsigned short h, l;
        split2(w, h, l);
        Aswz[i] = hl ? l : h;
    } else {                               // AOT border zero: 4*22704 shorts
        int idx = (blk-480)*256 + threadIdx.x;
        if (idx < BB*22704) {
            int b = idx / 22704;
            int r = idx % 22704;
            size_t off;
            if (r < 11440) {
                int row = (r < 5720) ? 0 : 129;
                int e   = (r < 5720) ? r : r - 5720;
                off = (size_t)b*AOT_IMGE + (size_t)row*AOT_ROWE + e;
            } else {
                int r2 = r - 11440;
                int rr = r2 / 88 + 1;
                int w2 = r2 % 88;
                int col = (w2 < 44) ? 0 : 129;
                int ci  = (w2 < 44) ? w2 : w2 - 44;
                off = (size_t)b*AOT_IMGE + (size_t)rr*AOT_ROWE
                    + (size_t)col*AOT_CI + ci;
            }
            AOT[off] = 0;
        }
    }
}

// ---------------------------------------------------------------------------
// K1: FUSED qkv -> energy -> (grid sync) -> softmax -> PV -> AOT.
// Cooperative launch, grid (64,B) = 256 blocks = 1/CU, 512 thr, 128.5KB LDS.
// Phase 1 (r11 pipeline, unchanged math): A image staged once; 16 rounds of
//   compute | pack-write next | issue loads r+3; Q,K(+bias)->qk tile, energy
//   partial -> Ep; V(+bias) stays in acc2 registers.
// grid.sync()
// Phase 2: each block reduces Ep (64 partials) + softmax -> at4[e][d] in LDS.
// Phase 3: PV from registers: AO[d][n] = sum_e at4[e][d]*Vreg; pair-combine
//   across lane halves; write bf16 AOT (padded layout).
// ---------------------------------------------------------------------------
__global__ __launch_bounds__(512, 2) void fused_attn_kernel(
    const float* __restrict__ x, const unsigned short* __restrict__ Aswz,
    const float* __restrict__ bq, const float* __restrict__ bk,
    const float* __restrict__ bv,
    float* __restrict__ Ep, unsigned short* __restrict__ AOT)
{
    __shared__ __align__(16) char lds[QKV_LDS];
    const int b    = blockIdx.y;
    const int s    = blockIdx.x;                 // 0..63
    const int n0   = s * 256;
    const int tid  = threadIdx.x;
    const int w    = tid >> 6;
    const int lane = tid & 63;
    const int l31  = lane & 31;
    const int lh   = lane >> 5;
    const int ch_a = tid >> 6;                   // 0..7
    const int f4   = tid & 63;                   // n-quad 0..63

    // stage A image (96 KB linear)
    for (int i = tid; i < 6144; i += 512)
        async_copy16(lds + i*16, (const char*)Aswz + i*16);
    float* biasL = (float*)(lds + 131072);
    if (tid < 96)
        biasL[tid] = (tid < 32) ? bq[tid] : (tid < 64) ? bk[tid-32] : bv[tid-64];

    unsigned int* stg[2] = { (unsigned int*)(lds + 98304),
                             (unsigned int*)(lds + 114688) };
    const float* xb = x + (size_t)b*CC*NN + n0 + f4*4;

    f32x16 acc0 = {0}, acc1 = {0}, acc2 = {0};

    float4 va0, vb0, va1, vb1, va2, vb2;
    #define LOADX(VA, VB, R) do { \
        VA = *(const float4*)(xb + (size_t)((R)*16 + ch_a    )*NN); \
        VB = *(const float4*)(xb + (size_t)((R)*16 + ch_a + 8)*NN); } while (0)
    #define PACKW(BUF, VA, VB) do { \
        uint4 ua, ub; \
        ua.x = packsplit((VA).x); ua.y = packsplit((VA).y); \
        ua.z = packsplit((VA).z); ua.w = packsplit((VA).w); \
        ub.x = packsplit((VB).x); ub.y = packsplit((VB).y); \
        ub.z = packsplit((VB).z); ub.w = packsplit((VB).w); \
        *(uint4*)((BUF) + (ch_a    )*256 + f4*4) = ua; \
        *(uint4*)((BUF) + (ch_a + 8)*256 + f4*4) = ub; } while (0)

    LOADX(va0, vb0, 0);
    LOADX(va1, vb1, 1);
    LOADX(va2, vb2, 2);
    PACKW(stg[0], va0, vb0);
    __syncthreads();

    #pragma unroll
    for (int r = 0; r < 16; ++r) {
        {
            const unsigned int* bufc = stg[r & 1];
            unsigned int u[8];
            #pragma unroll
            for (int j = 0; j < 8; ++j)
                u[j] = bufc[(lh*8 + j)*256 + 32*w + l31];
            union { bf16x8 v; unsigned int d[4]; } B1, B2;
            #pragma unroll
            for (int dq = 0; dq < 4; ++dq) {
                B1.d[dq] = (u[2*dq] & 0xFFFFu) | (u[2*dq+1] << 16);
                B2.d[dq] = (u[2*dq] >> 16)     | (u[2*dq+1] & 0xFFFF0000u);
            }
            #pragma unroll
            for (int cf = 0; cf < 3; ++cf) {
                bf16x8 ah = *(const bf16x8*)(lds + (((r*6 +     cf)*64) + lane)*16);
                bf16x8 al = *(const bf16x8*)(lds + (((r*6 + 3 + cf)*64) + lane)*16);
                f32x16* ac = (cf == 0) ? &acc0 : (cf == 1) ? &acc1 : &acc2;
                *ac = __builtin_amdgcn_mfma_f32_32x32x16_bf16(ah, B1.v, *ac, 0, 0, 0);
                *ac = __builtin_amdgcn_mfma_f32_32x32x16_bf16(ah, B2.v, *ac, 0, 0, 0);
                *ac = __builtin_amdgcn_mfma_f32_32x32x16_bf16(al, B1.v, *ac, 0, 0, 0);
                *ac = __builtin_amdgcn_mfma_f32_32x32x16_bf16(al, B2.v, *ac, 0, 0, 0);
            }
        }
        if (r < 15) {
            if ((r+1) % 3 == 0)      PACKW(stg[(r+1) & 1], va0, vb0);
            else if ((r+1) % 3 == 1) PACKW(stg[(r+1) & 1], va1, vb1);
            else                     PACKW(stg[(r+1) & 1], va2, vb2);
        }
        if (r + 3 < 16) {
            if ((r+3) % 3 == 0)      LOADX(va0, vb0, r+3);
            else if ((r+3) % 3 == 1) LOADX(va1, vb1, r+3);
            else                     LOADX(va2, vb2, r+3);
        }
        __syncthreads();
    }
    #undef LOADX
    #undef PACKW

    // ---- Q,K -> qk tile (A region dead); V stays in acc2 ----
    float* qk = (float*)lds;
    #pragma unroll
    for (int r = 0; r < 16; ++r) {
        const int rsub = (r & 3) + 8*(r >> 2) + 4*lh;
        const int col  = 32*w + l31;
        qk[rsub*QKVP + col]      = acc0[r] + biasL[rsub];
        qk[(32+rsub)*QKVP + col] = acc1[r] + biasL[32 + rsub];
    }
    __syncthreads();

    // ---- energy partial over this block's 256 n ----
    {
        const int d  = tid >> 4;
        const int e2 = tid & 15;
        const float* qrow = qk + d*QKVP;
        float s0 = 0.f, s1 = 0.f;
        for (int n4 = 0; n4 < 256; n4 += 4) {
            float4 qv = *(const float4*)(qrow + n4);
            float4 ka = *(const float4*)(qk + (32 + e2)*QKVP + n4);
            float4 kb = *(const float4*)(qk + (48 + e2)*QKVP + n4);
            s0 += qv.x*ka.x + qv.y*ka.y + qv.z*ka.z + qv.w*ka.w;
            s1 += qv.x*kb.x + qv.y*kb.y + qv.z*kb.z + qv.w*kb.w;
        }
        float* ep = Ep + ((size_t)s*BB + b)*1024;
        ep[d*32 + e2]      = s0;
        ep[d*32 + e2 + 16] = s1;
    }

    __threadfence();
    cg::this_grid().sync();

    // ---- phase 2: reduce 64 partials + softmax -> at4[e][36-pitch][d] ----
    float* at4 = (float*)(lds + 98304);
    {
        float e0s = 0.f, e1s = 0.f;
        #pragma unroll 8
        for (int p = 0; p < 64; ++p) {
            float2 v = *(const float2*)(Ep + ((size_t)p*BB + b)*1024 + 2*tid);
            e0s += v.x; e1s += v.y;
        }
        float nv0 = -e0s, nv1 = -e1s;
        float m = fmaxf(nv0, nv1);
        for (int off = 8; off > 0; off >>= 1) m = fmaxf(m, __shfl_xor(m, off, 16));
        float p0 = expf(nv0 - m), p1 = expf(nv1 - m);
        float su = p0 + p1;
        for (int off = 8; off > 0; off >>= 1) su += __shfl_xor(su, off, 16);
        const float inv = 1.0f / su;
        const int d = tid >> 4;
        const int e = 2*(tid & 15);
        at4[e*36 + d]     = p0 * inv;
        at4[(e+1)*36 + d] = p1 * inv;
    }
    __syncthreads();

    // ---- phase 3: PV from registers, pair-combine, write AOT bf16 ----
    {
        float accd[32];
        #pragma unroll
        for (int d = 0; d < 32; ++d) accd[d] = 0.f;
        #pragma unroll
        for (int r = 0; r < 16; ++r) {
            const int rsub = (r & 3) + 8*(r >> 2) + 4*lh;
            const float v = acc2[r] + biasL[64 + rsub];
            const float4* ar = (const float4*)(at4 + rsub*36);
            #pragma unroll
            for (int dq = 0; dq < 8; ++dq) {
                float4 a = ar[dq];
                accd[4*dq+0] += a.x * v; accd[4*dq+1] += a.y * v;
                accd[4*dq+2] += a.z * v; accd[4*dq+3] += a.w * v;
            }
        }
        #pragma unroll
        for (int d = 0; d < 32; ++d)
            accd[d] += __shfl_xor(accd[d], 32);
        // lane keeps d range [16*lh, 16*lh+16)
        float fin[16];
        #pragma unroll
        for (int j = 0; j < 16; ++j)
            fin[j] = lh ? accd[16 + j] : accd[j];
        const int n  = n0 + 32*w + l31;
        const int h  = n >> 7, ww = n & 127;
        unsigned short* dst = AOT + (size_t)b*AOT_IMGE + (size_t)(h+1)*AOT_ROWE
                                  + (size_t)(ww+1)*AOT_CI + 16*lh;
        #pragma unroll
        for (int q = 0; q < 4; ++q) {
            ushort4 u;
            u.x = f2bf(fin[4*q+0]); u.y = f2bf(fin[4*q+1]);
            u.z = f2bf(fin[4*q+2]); u.w = f2bf(fin[4*q+3]);
            *(ushort4*)(dst + 4*q) = u;
        }
    }
}

// ---------------------------------------------------------------------------
// K5: conv implicit-GEMM, 2 H-rows per block (unchanged).
// ---------------------------------------------------------------------------
__global__ __launch_bounds__(512, 1) void conv_kernel(
    const unsigned short* __restrict__ AOT, const unsigned short* __restrict__ Wt,
    const float* __restrict__ gammap, const float* __restrict__ x,
    float* __restrict__ out)
{
    __shared__ __align__(16) char lds[CONV_LDS];
    const int b   = blockIdx.y;
    const int h0  = blockIdx.x * 2;
    const int tid = threadIdx.x;
    const int wid = tid >> 6;
    const int lane = tid & 63;
    const int l15 = lane & 15;
    const int lj  = lane >> 4;
    const int wn  = wid & 1;
    const int wc  = wid >> 1;

    const char* psrc = (const char*)(AOT + (size_t)b*AOT_IMGE + (size_t)h0*AOT_ROWE);
    for (int i = tid; i < PATCH_SZ/16; i += 512)
        async_copy16(lds + i*16, psrc + i*16);
    for (int i = tid; i < WSLAB/16; i += 512)
        async_copy16(lds + PATCH_SZ + i*16, (const char*)Wt + i*16);
    __syncthreads();

    f32x4 acc[4][8];
    #pragma unroll
    for (int cf = 0; cf < 4; ++cf)
        #pragma unroll
        for (int nf = 0; nf < 8; ++nf)
            acc[cf][nf] = (f32x4){0.f, 0.f, 0.f, 0.f};

    for (int kk = 0; kk < 9; ++kk) {
        if (kk < 8) {
            const char* wsrc = (const char*)Wt + (size_t)(kk+1)*WSLAB;
            char* wdst = lds + PATCH_SZ + ((kk+1)&1)*WSLAB;
            for (int i = tid; i < WSLAB/16; i += 512)
                async_copy16(wdst + i*16, wsrc + i*16);
        }
        const int kh = kk / 3, kw = kk % 3;
        const char* wbase = lds + PATCH_SZ + (kk&1)*WSLAB;
        bf16x8 af[4];
        #pragma unroll
        for (int cf = 0; cf < 4; ++cf)
            af[cf] = ld_frag8(wbase + (wc*64 + cf*16 + l15)*88 + lj*16);
        #pragma unroll
        for (int nf = 0; nf < 8; ++nf) {
            const int cell = (wn + kh)*130 + nf*16 + l15 + kw;
            const bf16x8 bfr = ld_frag8(lds + cell*88 + lj*16);
            #pragma unroll
            for (int cf = 0; cf < 4; ++cf)
                acc[cf][nf] = __builtin_amdgcn_mfma_f32_16x16x32_bf16(
                    af[cf], bfr, acc[cf][nf], 0, 0, 0);
        }
        __syncthreads();
    }

    const float g0 = gammap[0];
    float* lf = (float*)lds;
    for (int k = 0; k < 4; ++k) {
        if (wc == k) {
            #pragma unroll
            for (int cf = 0; cf < 4; ++cf) {
                const int rl = cf*16 + 4*lj;
                #pragma unroll
                for (int nf = 0; nf < 8; ++nf) {
                    const int col = wn*128 + nf*16 + l15;
                    #pragma unroll
                    for (int j = 0; j < 4; ++j)
                        lf[(rl + j)*EPI_PITCH + col] = acc[cf][nf][j];
                }
            }
        }
        __syncthreads();
        #pragma unroll
        for (int it = 0; it < 8; ++it) {
            const int idx = tid + it*512;
            const int row = idx >> 6, c4 = idx & 63;
            const int co  = k*64 + row;
            const size_t g = ((size_t)b*CC + co)*NN + (size_t)h0*WW + c4*4;
            float4 v  = *(const float4*)(lf + row*EPI_PITCH + c4*4);
            float4 xv = *(const float4*)(x + g);
            float4 o;
            o.x = g0*gelu_fast(v.x) + xv.x;
            o.y = g0*gelu_fast(v.y) + xv.y;
            o.z = g0*gelu_fast(v.z) + xv.z;
            o.w = g0*gelu_fast(v.w) + xv.w;
            *(float4*)(out + g) = o;
        }
        __syncthreads();
    }
}

// ---------------------------------------------------------------------------
extern "C" void kernel_launch(void* const* d_in, const int* in_sizes, int n_in,
                              void* d_out, int out_size, void* d_ws, size_t ws_size,
                              hipStream_t stream)
{
    const float* x  = (const float*)d_in[0];
    const float* wq = (const float*)d_in[1];
    const float* bq = (const float*)d_in[2];
    const float* wk = (const float*)d_in[3];
    const float* bk = (const float*)d_in[4];
    const float* wv = (const float*)d_in[5];
    const float* bv = (const float*)d_in[6];
    const float* wp = (const float*)d_in[7];
    const float* gm = (const float*)d_in[8];
    float* out = (float*)d_out;

    char* ws = (char*)d_ws;
    unsigned short* AOT  = (unsigned short*)ws;
    unsigned short* Wt   = (unsigned short*)(ws + AOT_ALLOC);
    unsigned short* Aswz = (unsigned short*)(ws + AOT_ALLOC + WT_BYTES);
    float* Ep = (float*)(ws + AOT_ALLOC + WT_BYTES + ASWZ_BYTES);   // 1 MB

    prep_kernel<<<dim3(835), 256, 0, stream>>>(wp, Wt, wq, wk, wv, Aswz, AOT);

    {
        void* args[] = { (void*)&x, (void*)&Aswz, (void*)&bq, (void*)&bk,
                         (void*)&bv, (void*)&Ep, (void*)&AOT };
        hipLaunchCooperativeKernel((void*)fused_attn_kernel,
                                   dim3(64, BB), dim3(512), args, 0, stream);
    }

    conv_kernel<<<dim3(64, BB), 512, 0, stream>>>(AOT, Wt, gm, x, out);
}

// Round 13
// 159.003 us; speedup vs baseline: 1.0177x; 1.0177x over previous
//
#include <hip/hip_runtime.h>
#include <hip/hip_bf16.h>
#include <hip/hip_cooperative_groups.h>
#include <math.h>

#define BB 4
#define CC 256
#define HH 128
#define WW 128
#define NN (HH*WW)
#define DD 32

// AOT: attention output, bf16, spatially padded +1 border, ci padded 32->44.
#define AOT_CI   44
#define AOT_ROWE (130*AOT_CI)                  // shorts per padded row (5720)
#define AOT_IMGE (130*AOT_ROWE)                // shorts per batch (743600)
#define AOT_BYTES ((size_t)BB*AOT_IMGE*2)      // 5,948,800
#define AOT_ALLOC (AOT_BYTES + 1024)

#define WT_BYTES (9*256*AOT_CI*2)              // 202,752

// conv LDS geometry (2-row tile)
#define PATCH_SZ 45760                         // 4 padded rows * 130 * 88
#define WSLAB    22528                         // 256 co * 88
#define CONV_LDS (PATCH_SZ + 2*WSLAB)          // 90,816
#define EPI_PITCH 260

// fused qkv+attn: A image [16 kstep][hi/lo][3 cf][64 lane][16B] = 96 KB
#define ASWZ_BYTES 98304
#define QKVP 260                               // qk epilogue tile pitch (floats)
// LDS map: A/qk 0..98303 | stage bufs 98304,114688 (16KB ea) | bias 131072
// phase2 at4 reuses 98304 (32 rows x 36 pitch floats)
#define QKV_LDS 131584

typedef __attribute__((ext_vector_type(8)))  short bf16x8;
typedef __attribute__((ext_vector_type(4)))  float f32x4;
typedef __attribute__((ext_vector_type(16))) float f32x16;

namespace cg = cooperative_groups;

__device__ inline void async_copy16(void* lds, const void* g) {
    __builtin_amdgcn_global_load_lds(
        (const __attribute__((address_space(1))) unsigned int*)g,
        (__attribute__((address_space(3))) unsigned int*)lds, 16, 0, 0);
}

__device__ inline unsigned short f2bf(float f) {
    __hip_bfloat16 h = __float2bfloat16(f);
    return *reinterpret_cast<unsigned short*>(&h);
}

__device__ inline void split2(float v, unsigned short& h, unsigned short& l) {
    __hip_bfloat16 hb = __float2bfloat16(v);
    float r = v - __bfloat162float(hb);     // exact (Sterbenz)
    __hip_bfloat16 lb = __float2bfloat16(r);
    h = *reinterpret_cast<unsigned short*>(&hb);
    l = *reinterpret_cast<unsigned short*>(&lb);
}

// truncation split packed: low16 = bf16(hi), high16 = bf16(lo residual)
__device__ inline unsigned int packsplit(float v) {
    unsigned int fb = __float_as_uint(v);
    unsigned int hb = fb & 0xFFFF0000u;
    float r = v - __uint_as_float(hb);
    unsigned int lb = __float_as_uint(r) >> 16;
    return (hb >> 16) | (lb << 16);
}

// 8B+8B LDS load of a bf16x8 fragment (88B row pitch is only 8B-aligned)
__device__ inline bf16x8 ld_frag8(const char* p) {
    union { bf16x8 v; short4 h[2]; } u;
    u.h[0] = *(const short4*)(p);
    u.h[1] = *(const short4*)(p + 8);
    return u.v;
}

// A&S 7.1.26 erf approximation, |err| ~1e-6
__device__ inline float gelu_fast(float v) {
    float a = fabsf(v) * 0.70710678118654752f;
    float t = __fdividef(1.0f, fmaf(0.3275911f, a, 1.0f));
    float p = t * fmaf(t, fmaf(t, fmaf(t, fmaf(t, 1.061405429f, -1.453152027f),
                                       1.421413741f), -0.284496736f), 0.254829592f);
    float e = 1.0f - p * __expf(-a * a);
    float erfv = (v < 0.0f) ? -e : e;
    return 0.5f * v * (1.0f + erfv);
}

// ---------------------------------------------------------------------------
// K0: fused prep — conv weight repack | qkv A-pack | AOT border zero.
// ---------------------------------------------------------------------------
__global__ __launch_bounds__(256) void prep_kernel(
    const float* __restrict__ wp, unsigned short* __restrict__ Wt,
    const float* __restrict__ wq, const float* __restrict__ wk,
    const float* __restrict__ wv, unsigned short* __restrict__ Aswz,
    unsigned short* __restrict__ AOT)
{
    const int blk = blockIdx.x;
    if (blk < 288) {                       // conv weights: 9*256*32 = 73728
        int i = blk*256 + threadIdx.x;
        int kk = i / (256*32);
        int r  = i % (256*32);
        int co = r >> 5, ci = r & 31;
        float v = wp[((size_t)co*32 + ci)*9 + kk];
        Wt[((size_t)kk*256 + co)*AOT_CI + ci] = f2bf(v);
    } else if (blk < 480) {                // qkv A image: 49152 entries
        int i = (blk-288)*256 + threadIdx.x;
        int j    = i & 7;
        int lane = (i >> 3) & 63;
        int q9   = i >> 9;                 // (s*2+hl)*3 + cf, 0..95
        int cf   = q9 % 3;
        int t    = q9 / 3;
        int hl   = t & 1;
        int s    = t >> 1;                 // 0..15
        int row  = cf*32 + (lane & 31);
        int c    = s*16 + (lane >> 5)*8 + j;
        float w  = (row < 32) ? wq[row*256 + c]
                 : (row < 64) ? wk[(row-32)*256 + c]
                              : wv[(row-64)*256 + c];
        unsigned short h, l;
        split2(w, h, l);
        Aswz[i] = hl ? l : h;
    } else {                               // AOT border zero: 4*22704 shorts
        int idx = (blk-480)*256 + threadIdx.x;
        if (idx < BB*22704) {
            int b = idx / 22704;
            int r = idx % 22704;
            size_t off;
            if (r < 11440) {
                int row = (r < 5720) ? 0 : 129;
                int e   = (r < 5720) ? r : r - 5720;
                off = (size_t)b*AOT_IMGE + (size_t)row*AOT_ROWE + e;
            } else {
                int r2 = r - 11440;
                int rr = r2 / 88 + 1;
                int w2 = r2 % 88;
                int col = (w2 < 44) ? 0 : 129;
                int ci  = (w2 < 44) ? w2 : w2 - 44;
                off = (size_t)b*AOT_IMGE + (size_t)rr*AOT_ROWE
                    + (size_t)col*AOT_CI + ci;
            }
            AOT[off] = 0;
        }
    }
}

// ---------------------------------------------------------------------------
// K1: FUSED qkv -> energy -> (grid sync) -> softmax -> PV -> AOT.
// Cooperative launch, grid (64,B) = 256 blocks = 1/CU (LDS 128.5KB pins this),
// 512 thr.  __launch_bounds__(512,1): r12's (512,2) capped VGPR at 108 and
// spilled the 48-VGPR accumulator set to scratch (106us, MfmaUtil 4.5%).
// Phase 1 (r11 pipeline): A image staged once; 16 rounds of
//   compute | pack-write next | issue loads r+3; Q,K(+bias)->qk tile, energy
//   partial -> Ep; V(+bias) stays in acc2 registers.
// grid.sync()
// Phase 2: each block reduces Ep (64 partials) + softmax -> at4[e][d] in LDS.
// Phase 3: PV from registers; pair-combine across lane halves; bf16 AOT write.
// ---------------------------------------------------------------------------
__global__ __launch_bounds__(512, 1) void fused_attn_kernel(
    const float* __restrict__ x, const unsigned short* __restrict__ Aswz,
    const float* __restrict__ bq, const float* __restrict__ bk,
    const float* __restrict__ bv,
    float* __restrict__ Ep, unsigned short* __restrict__ AOT)
{
    __shared__ __align__(16) char lds[QKV_LDS];
    const int b    = blockIdx.y;
    const int s    = blockIdx.x;                 // 0..63
    const int n0   = s * 256;
    const int tid  = threadIdx.x;
    const int w    = tid >> 6;
    const int lane = tid & 63;
    const int l31  = lane & 31;
    const int lh   = lane >> 5;
    const int ch_a = tid >> 6;                   // 0..7
    const int f4   = tid & 63;                   // n-quad 0..63

    // stage A image (96 KB linear)
    for (int i = tid; i < 6144; i += 512)
        async_copy16(lds + i*16, (const char*)Aswz + i*16);
    float* biasL = (float*)(lds + 131072);
    if (tid < 96)
        biasL[tid] = (tid < 32) ? bq[tid] : (tid < 64) ? bk[tid-32] : bv[tid-64];

    unsigned int* stg[2] = { (unsigned int*)(lds + 98304),
                             (unsigned int*)(lds + 114688) };
    const float* xb = x + (size_t)b*CC*NN + n0 + f4*4;

    f32x16 acc0 = {0}, acc1 = {0}, acc2 = {0};

    float4 va0, vb0, va1, vb1, va2, vb2;
    #define LOADX(VA, VB, R) do { \
        VA = *(const float4*)(xb + (size_t)((R)*16 + ch_a    )*NN); \
        VB = *(const float4*)(xb + (size_t)((R)*16 + ch_a + 8)*NN); } while (0)
    #define PACKW(BUF, VA, VB) do { \
        uint4 ua, ub; \
        ua.x = packsplit((VA).x); ua.y = packsplit((VA).y); \
        ua.z = packsplit((VA).z); ua.w = packsplit((VA).w); \
        ub.x = packsplit((VB).x); ub.y = packsplit((VB).y); \
        ub.z = packsplit((VB).z); ub.w = packsplit((VB).w); \
        *(uint4*)((BUF) + (ch_a    )*256 + f4*4) = ua; \
        *(uint4*)((BUF) + (ch_a + 8)*256 + f4*4) = ub; } while (0)

    LOADX(va0, vb0, 0);
    LOADX(va1, vb1, 1);
    LOADX(va2, vb2, 2);
    PACKW(stg[0], va0, vb0);
    __syncthreads();

    #pragma unroll
    for (int r = 0; r < 16; ++r) {
        {
            const unsigned int* bufc = stg[r & 1];
            unsigned int u[8];
            #pragma unroll
            for (int j = 0; j < 8; ++j)
                u[j] = bufc[(lh*8 + j)*256 + 32*w + l31];
            union { bf16x8 v; unsigned int d[4]; } B1, B2;
            #pragma unroll
            for (int dq = 0; dq < 4; ++dq) {
                B1.d[dq] = (u[2*dq] & 0xFFFFu) | (u[2*dq+1] << 16);
                B2.d[dq] = (u[2*dq] >> 16)     | (u[2*dq+1] & 0xFFFF0000u);
            }
            #pragma unroll
            for (int cf = 0; cf < 3; ++cf) {
                bf16x8 ah = *(const bf16x8*)(lds + (((r*6 +     cf)*64) + lane)*16);
                bf16x8 al = *(const bf16x8*)(lds + (((r*6 + 3 + cf)*64) + lane)*16);
                f32x16* ac = (cf == 0) ? &acc0 : (cf == 1) ? &acc1 : &acc2;
                *ac = __builtin_amdgcn_mfma_f32_32x32x16_bf16(ah, B1.v, *ac, 0, 0, 0);
                *ac = __builtin_amdgcn_mfma_f32_32x32x16_bf16(ah, B2.v, *ac, 0, 0, 0);
                *ac = __builtin_amdgcn_mfma_f32_32x32x16_bf16(al, B1.v, *ac, 0, 0, 0);
                *ac = __builtin_amdgcn_mfma_f32_32x32x16_bf16(al, B2.v, *ac, 0, 0, 0);
            }
        }
        if (r < 15) {
            if ((r+1) % 3 == 0)      PACKW(stg[(r+1) & 1], va0, vb0);
            else if ((r+1) % 3 == 1) PACKW(stg[(r+1) & 1], va1, vb1);
            else                     PACKW(stg[(r+1) & 1], va2, vb2);
        }
        if (r + 3 < 16) {
            if ((r+3) % 3 == 0)      LOADX(va0, vb0, r+3);
            else if ((r+3) % 3 == 1) LOADX(va1, vb1, r+3);
            else                     LOADX(va2, vb2, r+3);
        }
        __syncthreads();
    }
    #undef LOADX
    #undef PACKW

    // ---- Q,K -> qk tile (A region dead); V stays in acc2 ----
    float* qk = (float*)lds;
    #pragma unroll
    for (int r = 0; r < 16; ++r) {
        const int rsub = (r & 3) + 8*(r >> 2) + 4*lh;
        const int col  = 32*w + l31;
        qk[rsub*QKVP + col]      = acc0[r] + biasL[rsub];
        qk[(32+rsub)*QKVP + col] = acc1[r] + biasL[32 + rsub];
    }
    __syncthreads();

    // ---- energy partial over this block's 256 n ----
    {
        const int d  = tid >> 4;
        const int e2 = tid & 15;
        const float* qrow = qk + d*QKVP;
        float s0 = 0.f, s1 = 0.f;
        for (int n4 = 0; n4 < 256; n4 += 4) {
            float4 qv = *(const float4*)(qrow + n4);
            float4 ka = *(const float4*)(qk + (32 + e2)*QKVP + n4);
            float4 kb = *(const float4*)(qk + (48 + e2)*QKVP + n4);
            s0 += qv.x*ka.x + qv.y*ka.y + qv.z*ka.z + qv.w*ka.w;
            s1 += qv.x*kb.x + qv.y*kb.y + qv.z*kb.z + qv.w*kb.w;
        }
        float* ep = Ep + ((size_t)s*BB + b)*1024;
        ep[d*32 + e2]      = s0;
        ep[d*32 + e2 + 16] = s1;
    }

    __threadfence();
    cg::this_grid().sync();

    // ---- phase 2: reduce 64 partials + softmax -> at4[e][36-pitch][d] ----
    float* at4 = (float*)(lds + 98304);
    {
        float e0s = 0.f, e1s = 0.f;
        #pragma unroll 8
        for (int p = 0; p < 64; ++p) {
            float2 v = *(const float2*)(Ep + ((size_t)p*BB + b)*1024 + 2*tid);
            e0s += v.x; e1s += v.y;
        }
        float nv0 = -e0s, nv1 = -e1s;
        float m = fmaxf(nv0, nv1);
        for (int off = 8; off > 0; off >>= 1) m = fmaxf(m, __shfl_xor(m, off, 16));
        float p0 = expf(nv0 - m), p1 = expf(nv1 - m);
        float su = p0 + p1;
        for (int off = 8; off > 0; off >>= 1) su += __shfl_xor(su, off, 16);
        const float inv = 1.0f / su;
        const int d = tid >> 4;
        const int e = 2*(tid & 15);
        at4[e*36 + d]     = p0 * inv;
        at4[(e+1)*36 + d] = p1 * inv;
    }
    __syncthreads();

    // ---- phase 3: PV from registers, pair-combine, write AOT bf16 ----
    {
        float accd[32];
        #pragma unroll
        for (int d = 0; d < 32; ++d) accd[d] = 0.f;
        #pragma unroll
        for (int r = 0; r < 16; ++r) {
            const int rsub = (r & 3) + 8*(r >> 2) + 4*lh;
            const float v = acc2[r] + biasL[64 + rsub];
            const float4* ar = (const float4*)(at4 + rsub*36);
            #pragma unroll
            for (int dq = 0; dq < 8; ++dq) {
                float4 a = ar[dq];
                accd[4*dq+0] += a.x * v; accd[4*dq+1] += a.y * v;
                accd[4*dq+2] += a.z * v; accd[4*dq+3] += a.w * v;
            }
        }
        #pragma unroll
        for (int d = 0; d < 32; ++d)
            accd[d] += __shfl_xor(accd[d], 32);
        // lane keeps d range [16*lh, 16*lh+16)
        float fin[16];
        #pragma unroll
        for (int j = 0; j < 16; ++j)
            fin[j] = lh ? accd[16 + j] : accd[j];
        const int n  = n0 + 32*w + l31;
        const int h  = n >> 7, ww = n & 127;
        unsigned short* dst = AOT + (size_t)b*AOT_IMGE + (size_t)(h+1)*AOT_ROWE
                                  + (size_t)(ww+1)*AOT_CI + 16*lh;
        #pragma unroll
        for (int q = 0; q < 4; ++q) {
            ushort4 u;
            u.x = f2bf(fin[4*q+0]); u.y = f2bf(fin[4*q+1]);
            u.z = f2bf(fin[4*q+2]); u.w = f2bf(fin[4*q+3]);
            *(ushort4*)(dst + 4*q) = u;
        }
    }
}

// ---------------------------------------------------------------------------
// K5: conv implicit-GEMM, 2 H-rows per block (unchanged).
// ---------------------------------------------------------------------------
__global__ __launch_bounds__(512, 1) void conv_kernel(
    const unsigned short* __restrict__ AOT, const unsigned short* __restrict__ Wt,
    const float* __restrict__ gammap, const float* __restrict__ x,
    float* __restrict__ out)
{
    __shared__ __align__(16) char lds[CONV_LDS];
    const int b   = blockIdx.y;
    const int h0  = blockIdx.x * 2;
    const int tid = threadIdx.x;
    const int wid = tid >> 6;
    const int lane = tid & 63;
    const int l15 = lane & 15;
    const int lj  = lane >> 4;
    const int wn  = wid & 1;
    const int wc  = wid >> 1;

    const char* psrc = (const char*)(AOT + (size_t)b*AOT_IMGE + (size_t)h0*AOT_ROWE);
    for (int i = tid; i < PATCH_SZ/16; i += 512)
        async_copy16(lds + i*16, psrc + i*16);
    for (int i = tid; i < WSLAB/16; i += 512)
        async_copy16(lds + PATCH_SZ + i*16, (const char*)Wt + i*16);
    __syncthreads();

    f32x4 acc[4][8];
    #pragma unroll
    for (int cf = 0; cf < 4; ++cf)
        #pragma unroll
        for (int nf = 0; nf < 8; ++nf)
            acc[cf][nf] = (f32x4){0.f, 0.f, 0.f, 0.f};

    for (int kk = 0; kk < 9; ++kk) {
        if (kk < 8) {
            const char* wsrc = (const char*)Wt + (size_t)(kk+1)*WSLAB;
            char* wdst = lds + PATCH_SZ + ((kk+1)&1)*WSLAB;
            for (int i = tid; i < WSLAB/16; i += 512)
                async_copy16(wdst + i*16, wsrc + i*16);
        }
        const int kh = kk / 3, kw = kk % 3;
        const char* wbase = lds + PATCH_SZ + (kk&1)*WSLAB;
        bf16x8 af[4];
        #pragma unroll
        for (int cf = 0; cf < 4; ++cf)
            af[cf] = ld_frag8(wbase + (wc*64 + cf*16 + l15)*88 + lj*16);
        #pragma unroll
        for (int nf = 0; nf < 8; ++nf) {
            const int cell = (wn + kh)*130 + nf*16 + l15 + kw;
            const bf16x8 bfr = ld_frag8(lds + cell*88 + lj*16);
            #pragma unroll
            for (int cf = 0; cf < 4; ++cf)
                acc[cf][nf] = __builtin_amdgcn_mfma_f32_16x16x32_bf16(
                    af[cf], bfr, acc[cf][nf], 0, 0, 0);
        }
        __syncthreads();
    }

    const float g0 = gammap[0];
    float* lf = (float*)lds;
    for (int k = 0; k < 4; ++k) {
        if (wc == k) {
            #pragma unroll
            for (int cf = 0; cf < 4; ++cf) {
                const int rl = cf*16 + 4*lj;
                #pragma unroll
                for (int nf = 0; nf < 8; ++nf) {
                    const int col = wn*128 + nf*16 + l15;
                    #pragma unroll
                    for (int j = 0; j < 4; ++j)
                        lf[(rl + j)*EPI_PITCH + col] = acc[cf][nf][j];
                }
            }
        }
        __syncthreads();
        #pragma unroll
        for (int it = 0; it < 8; ++it) {
            const int idx = tid + it*512;
            const int row = idx >> 6, c4 = idx & 63;
            const int co  = k*64 + row;
            const size_t g = ((size_t)b*CC + co)*NN + (size_t)h0*WW + c4*4;
            float4 v  = *(const float4*)(lf + row*EPI_PITCH + c4*4);
            float4 xv = *(const float4*)(x + g);
            float4 o;
            o.x = g0*gelu_fast(v.x) + xv.x;
            o.y = g0*gelu_fast(v.y) + xv.y;
            o.z = g0*gelu_fast(v.z) + xv.z;
            o.w = g0*gelu_fast(v.w) + xv.w;
            *(float4*)(out + g) = o;
        }
        __syncthreads();
    }
}

// ---------------------------------------------------------------------------
extern "C" void kernel_launch(void* const* d_in, const int* in_sizes, int n_in,
                              void* d_out, int out_size, void* d_ws, size_t ws_size,
                              hipStream_t stream)
{
    const float* x  = (const float*)d_in[0];
    const float* wq = (const float*)d_in[1];
    const float* bq = (const float*)d_in[2];
    const float* wk = (const float*)d_in[3];
    const float* bk = (const float*)d_in[4];
    const float* wv = (const float*)d_in[5];
    const float* bv = (const float*)d_in[6];
    const float* wp = (const float*)d_in[7];
    const float* gm = (const float*)d_in[8];
    float* out = (float*)d_out;

    char* ws = (char*)d_ws;
    unsigned short* AOT  = (unsigned short*)ws;
    unsigned short* Wt   = (unsigned short*)(ws + AOT_ALLOC);
    unsigned short* Aswz = (unsigned short*)(ws + AOT_ALLOC + WT_BYTES);
    float* Ep = (float*)(ws + AOT_ALLOC + WT_BYTES + ASWZ_BYTES);   // 1 MB

    prep_kernel<<<dim3(835), 256, 0, stream>>>(wp, Wt, wq, wk, wv, Aswz, AOT);

    {
        void* args[] = { (void*)&x, (void*)&Aswz, (void*)&bq, (void*)&bk,
                         (void*)&bv, (void*)&Ep, (void*)&AOT };
        hipLaunchCooperativeKernel((void*)fused_attn_kernel,
                                   dim3(64, BB), dim3(512), args, 0, stream);
    }

    conv_kernel<<<dim3(64, BB), 512, 0, stream>>>(AOT, Wt, gm, x, out);
}

// Round 14
// 79.875 us; speedup vs baseline: 2.0259x; 1.9906x over previous
//
#include <hip/hip_runtime.h>
#include <hip/hip_bf16.h>
#include <math.h>

#define BB 4
#define CC 256
#define HH 128
#define WW 128
#define NN (HH*WW)
#define DD 32

// AOT: attention output, bf16, spatially padded +1 border, ci padded 32->44.
#define AOT_CI   44
#define AOT_ROWE (130*AOT_CI)                  // shorts per padded row (5720)
#define AOT_IMGE (130*AOT_ROWE)                // shorts per batch (743600)
#define AOT_BYTES ((size_t)BB*AOT_IMGE*2)      // 5,948,800
#define AOT_ALLOC (AOT_BYTES + 1024)

#define WT_BYTES (9*256*AOT_CI*2)              // 202,752

// conv LDS geometry (2-row tile)
#define PATCH_SZ 45760                         // 4 padded rows * 130 * 88
#define WSLAB    22528                         // 256 co * 88
#define CONV_LDS (PATCH_SZ + 2*WSLAB)          // 90,816
#define EPI_PITCH 260

// qkv: A image [16 kstep][hi/lo][3 cf][64 lane][16B] = 96 KB
#define ASWZ_BYTES 98304
#define QKVP 260                               // qk epilogue tile pitch (floats)
// LDS map: A/qk 0..98303 | wave-private stage 98304 + w*4096 + buf*2048
//          (8 waves x 2 bufs x 2KB = 32KB) | bias 131072
#define QKV_LDS 131584

typedef __attribute__((ext_vector_type(8)))  short bf16x8;
typedef __attribute__((ext_vector_type(4)))  float f32x4;
typedef __attribute__((ext_vector_type(16))) float f32x16;

__device__ inline void async_copy16(void* lds, const void* g) {
    __builtin_amdgcn_global_load_lds(
        (const __attribute__((address_space(1))) unsigned int*)g,
        (__attribute__((address_space(3))) unsigned int*)lds, 16, 0, 0);
}

__device__ inline unsigned short f2bf(float f) {
    __hip_bfloat16 h = __float2bfloat16(f);
    return *reinterpret_cast<unsigned short*>(&h);
}

__device__ inline void split2(float v, unsigned short& h, unsigned short& l) {
    __hip_bfloat16 hb = __float2bfloat16(v);
    float r = v - __bfloat162float(hb);     // exact (Sterbenz)
    __hip_bfloat16 lb = __float2bfloat16(r);
    h = *reinterpret_cast<unsigned short*>(&hb);
    l = *reinterpret_cast<unsigned short*>(&lb);
}

// truncation split packed: low16 = bf16(hi), high16 = bf16(lo residual)
__device__ inline unsigned int packsplit(float v) {
    unsigned int fb = __float_as_uint(v);
    unsigned int hb = fb & 0xFFFF0000u;
    float r = v - __uint_as_float(hb);
    unsigned int lb = __float_as_uint(r) >> 16;
    return (hb >> 16) | (lb << 16);
}

// 8B+8B LDS load of a bf16x8 fragment (88B row pitch is only 8B-aligned)
__device__ inline bf16x8 ld_frag8(const char* p) {
    union { bf16x8 v; short4 h[2]; } u;
    u.h[0] = *(const short4*)(p);
    u.h[1] = *(const short4*)(p + 8);
    return u.v;
}

// A&S 7.1.26 erf approximation, |err| ~1e-6
__device__ inline float gelu_fast(float v) {
    float a = fabsf(v) * 0.70710678118654752f;
    float t = __fdividef(1.0f, fmaf(0.3275911f, a, 1.0f));
    float p = t * fmaf(t, fmaf(t, fmaf(t, fmaf(t, 1.061405429f, -1.453152027f),
                                       1.421413741f), -0.284496736f), 0.254829592f);
    float e = 1.0f - p * __expf(-a * a);
    float erfv = (v < 0.0f) ? -e : e;
    return 0.5f * v * (1.0f + erfv);
}

// ---------------------------------------------------------------------------
// K0: fused prep — conv weight repack | qkv A-pack | AOT border zero.
// ---------------------------------------------------------------------------
__global__ __launch_bounds__(256) void prep_kernel(
    const float* __restrict__ wp, unsigned short* __restrict__ Wt,
    const float* __restrict__ wq, const float* __restrict__ wk,
    const float* __restrict__ wv, unsigned short* __restrict__ Aswz,
    unsigned short* __restrict__ AOT)
{
    const int blk = blockIdx.x;
    if (blk < 288) {                       // conv weights: 9*256*32 = 73728
        int i = blk*256 + threadIdx.x;
        int kk = i / (256*32);
        int r  = i % (256*32);
        int co = r >> 5, ci = r & 31;
        float v = wp[((size_t)co*32 + ci)*9 + kk];
        Wt[((size_t)kk*256 + co)*AOT_CI + ci] = f2bf(v);
    } else if (blk < 480) {                // qkv A image: 49152 entries
        int i = (blk-288)*256 + threadIdx.x;
        int j    = i & 7;
        int lane = (i >> 3) & 63;
        int q9   = i >> 9;                 // (s*2+hl)*3 + cf, 0..95
        int cf   = q9 % 3;
        int t    = q9 / 3;
        int hl   = t & 1;
        int s    = t >> 1;                 // 0..15
        int row  = cf*32 + (lane & 31);
        int c    = s*16 + (lane >> 5)*8 + j;
        float w  = (row < 32) ? wq[row*256 + c]
                 : (row < 64) ? wk[(row-32)*256 + c]
                              : wv[(row-64)*256 + c];
        unsigned short h, l;
        split2(w, h, l);
        Aswz[i] = hl ? l : h;
    } else {                               // AOT border zero: 4*22704 shorts
        int idx = (blk-480)*256 + threadIdx.x;
        if (idx < BB*22704) {
            int b = idx / 22704;
            int r = idx % 22704;
            size_t off;
            if (r < 11440) {
                int row = (r < 5720) ? 0 : 129;
                int e   = (r < 5720) ? r : r - 5720;
                off = (size_t)b*AOT_IMGE + (size_t)row*AOT_ROWE + e;
            } else {
                int r2 = r - 11440;
                int rr = r2 / 88 + 1;
                int w2 = r2 % 88;
                int col = (w2 < 44) ? 0 : 129;
                int ci  = (w2 < 44) ? w2 : w2 - 44;
                off = (size_t)b*AOT_IMGE + (size_t)rr*AOT_ROWE
                    + (size_t)col*AOT_CI + ci;
            }
            AOT[off] = 0;
        }
    }
}

// ---------------------------------------------------------------------------
// K1: QKV MFMA GEMM v7 — BARRIER-FREE K-loop via wave-private staging.
// grid (64 n-tiles of 256, B), 512 thr = 8 waves; wave w owns n [32w,32w+32).
// A image (96 KB) staged once (single barrier).  16 rounds of 16 channels:
// each wave loads ITS OWN 16ch x 32n chunk (2 float4/lane, 8x128B coalesced
// segments), packs to a wave-private 2KB LDS double-buffer, computes 12 MFMA.
// No __syncthreads in the loop — per-wave lgkmcnt orders ds_write->ds_read,
// waves free-run, keeping ~48KB/CU of loads in flight (vs ~0 at each barrier
// in the r7-r13 lockstep variants, the measured 3x streaming-efficiency loss).
// Schedule per round r: LOAD(r+3) | COMPUTE(r) | PACK(r+1).
// Epilogue (= r11): Q,K(+bias)->qk tile, V(+bias)->global, energy partial
// E[32][32] over 256 n -> Ep (64 partial sets).
// ---------------------------------------------------------------------------
__global__ __launch_bounds__(512, 1) void qkv_mfma_kernel(
    const float* __restrict__ x, const unsigned short* __restrict__ Aswz,
    const float* __restrict__ bq, const float* __restrict__ bk,
    const float* __restrict__ bv,
    float* __restrict__ Vout, float* __restrict__ Ep)
{
    __shared__ __align__(16) char lds[QKV_LDS];
    const int b    = blockIdx.y;
    const int s    = blockIdx.x;                 // 0..63
    const int n0   = s * 256;
    const int tid  = threadIdx.x;
    const int w    = tid >> 6;
    const int lane = tid & 63;
    const int l31  = lane & 31;
    const int lh   = lane >> 5;
    const int chl  = lane >> 3;                  // 0..7 loader channel
    const int nq   = lane & 7;                   // loader n-quad

    // stage A image (96 KB linear)
    for (int i = tid; i < 6144; i += 512)
        async_copy16(lds + i*16, (const char*)Aswz + i*16);
    float* biasL = (float*)(lds + 131072);
    if (tid < 96)
        biasL[tid] = (tid < 32) ? bq[tid] : (tid < 64) ? bk[tid-32] : bv[tid-64];

    char* mybuf = lds + 98304 + w*4096;          // wave-private 2 x 2KB
    const float* xq4 = x + (size_t)b*CC*NN + n0 + 32*w + nq*4;

    f32x16 acc0 = {0}, acc1 = {0}, acc2 = {0};

    float4 sa0, sb0, sa1, sb1, sa2, sb2;
    #define LOADX(VA, VB, R) do { \
        VA = *(const float4*)(xq4 + (size_t)((R)*16 + chl    )*NN); \
        VB = *(const float4*)(xq4 + (size_t)((R)*16 + 8 + chl)*NN); } while (0)
    #define PACKW(R, VA, VB) do { \
        unsigned int* bp = (unsigned int*)(mybuf + ((R) & 1)*2048); \
        uint4 ua, ub; \
        ua.x = packsplit((VA).x); ua.y = packsplit((VA).y); \
        ua.z = packsplit((VA).z); ua.w = packsplit((VA).w); \
        ub.x = packsplit((VB).x); ub.y = packsplit((VB).y); \
        ub.z = packsplit((VB).z); ub.w = packsplit((VB).w); \
        *(uint4*)(bp + (chl    )*32 + nq*4) = ua; \
        *(uint4*)(bp + (8 + chl)*32 + nq*4) = ub; } while (0)

    LOADX(sa0, sb0, 0);
    LOADX(sa1, sb1, 1);
    LOADX(sa2, sb2, 2);
    PACKW(0, sa0, sb0);
    __syncthreads();                             // A image resident (only barrier)

    #pragma unroll
    for (int r = 0; r < 16; ++r) {
        // issue loads for round r+3 (3-round lead, wave-private)
        if (r + 3 < 16) {
            if ((r+3) % 3 == 0)      LOADX(sa0, sb0, r+3);
            else if ((r+3) % 3 == 1) LOADX(sa1, sb1, r+3);
            else                     LOADX(sa2, sb2, r+3);
        }
        // compute round r from own buf[r&1]
        {
            const unsigned int* bufc = (const unsigned int*)(mybuf + (r & 1)*2048);
            unsigned int u[8];
            #pragma unroll
            for (int j = 0; j < 8; ++j)
                u[j] = bufc[(lh*8 + j)*32 + l31];
            union { bf16x8 v; unsigned int d[4]; } B1, B2;
            #pragma unroll
            for (int dq = 0; dq < 4; ++dq) {
                B1.d[dq] = (u[2*dq] & 0xFFFFu) | (u[2*dq+1] << 16);
                B2.d[dq] = (u[2*dq] >> 16)     | (u[2*dq+1] & 0xFFFF0000u);
            }
            #pragma unroll
            for (int cf = 0; cf < 3; ++cf) {
                bf16x8 ah = *(const bf16x8*)(lds + (((r*6 +     cf)*64) + lane)*16);
                bf16x8 al = *(const bf16x8*)(lds + (((r*6 + 3 + cf)*64) + lane)*16);
                f32x16* ac = (cf == 0) ? &acc0 : (cf == 1) ? &acc1 : &acc2;
                *ac = __builtin_amdgcn_mfma_f32_32x32x16_bf16(ah, B1.v, *ac, 0, 0, 0);
                *ac = __builtin_amdgcn_mfma_f32_32x32x16_bf16(ah, B2.v, *ac, 0, 0, 0);
                *ac = __builtin_amdgcn_mfma_f32_32x32x16_bf16(al, B1.v, *ac, 0, 0, 0);
                *ac = __builtin_amdgcn_mfma_f32_32x32x16_bf16(al, B2.v, *ac, 0, 0, 0);
            }
        }
        // pack round r+1 into the other private buffer
        if (r + 1 < 16) {
            if ((r+1) % 3 == 0)      PACKW(r+1, sa0, sb0);
            else if ((r+1) % 3 == 1) PACKW(r+1, sa1, sb1);
            else                     PACKW(r+1, sa2, sb2);
        }
    }
    #undef LOADX
    #undef PACKW

    // ---- epilogue: Q,K -> qk tile (A region dead), V -> global ----
    __syncthreads();
    float* qk = (float*)lds;
    #pragma unroll
    for (int r = 0; r < 16; ++r) {
        const int rsub = (r & 3) + 8*(r >> 2) + 4*lh;
        const int col  = 32*w + l31;
        qk[rsub*QKVP + col]      = acc0[r] + biasL[rsub];
        qk[(32+rsub)*QKVP + col] = acc1[r] + biasL[32 + rsub];
        Vout[((size_t)b*DD + rsub)*NN + n0 + col] = acc2[r] + biasL[64 + rsub];
    }
    __syncthreads();

    // ---- energy partial: E[d][e] = sum_n Q[d][n]*K[e][n] over 256 n ----
    const int d  = tid >> 4;                     // 0..31
    const int e2 = tid & 15;                     // handles e2 and e2+16
    const float* qrow = qk + d*QKVP;
    float s0 = 0.f, s1 = 0.f;
    for (int n4 = 0; n4 < 256; n4 += 4) {
        float4 qv = *(const float4*)(qrow + n4);
        float4 ka = *(const float4*)(qk + (32 + e2)*QKVP + n4);
        float4 kb = *(const float4*)(qk + (48 + e2)*QKVP + n4);
        s0 += qv.x*ka.x + qv.y*ka.y + qv.z*ka.z + qv.w*ka.w;
        s1 += qv.x*kb.x + qv.y*kb.y + qv.z*kb.z + qv.w*kb.w;
    }
    float* ep = Ep + ((size_t)s*BB + b)*1024;
    ep[d*32 + e2]      = s0;
    ep[d*32 + e2 + 16] = s1;
}

// ---------------------------------------------------------------------------
// K3: softmax over 64 partials.  softmax(max-E)==softmax(-E).
// ---------------------------------------------------------------------------
__global__ __launch_bounds__(1024) void softmax_kernel(
    const float* __restrict__ Ep, float* __restrict__ attT)
{
    const int b = blockIdx.x;
    const int e = threadIdx.x, d = threadIdx.y;
    float s = 0.f;
    #pragma unroll 8
    for (int p = 0; p < 64; ++p)
        s += Ep[((size_t)p * BB + b) * (DD * DD) + d * DD + e];
    float nv = -s;
    float m = nv;
    for (int off = 16; off > 0; off >>= 1) m = fmaxf(m, __shfl_xor(m, off, 32));
    float pe = expf(nv - m);
    float su = pe;
    for (int off = 16; off > 0; off >>= 1) su += __shfl_xor(su, off, 32);
    attT[(size_t)b * (DD * DD) + e * DD + d] = pe / su;
}

// ---------------------------------------------------------------------------
// K4: PV — reads standalone V[b][32][N]; writes bf16 AOT padded layout.
// ---------------------------------------------------------------------------
__global__ __launch_bounds__(256) void pv_kernel(
    const float* __restrict__ V, const float* __restrict__ attT,
    unsigned short* __restrict__ AOT)
{
    __shared__ float Vs[DD][128];
    __shared__ float at4[DD][DD];        // [e][d]
    const int b  = blockIdx.y;
    const int n0 = blockIdx.x * 128;
    const int tid = threadIdx.x;
    for (int i = tid; i < 1024; i += 256) {
        int r = i >> 5, c4 = i & 31;
        *(float4*)&Vs[r][c4*4] =
            *(const float4*)(V + ((size_t)b*DD + r)*NN + n0 + c4*4);
    }
    for (int i = tid; i < 1024; i += 256)
        at4[i >> 5][i & 31] = attT[(size_t)b*1024 + i];
    __syncthreads();
    const int nl = tid & 127;
    const int dg = tid >> 7;
    float acc[16];
    #pragma unroll
    for (int k = 0; k < 16; ++k) acc[k] = 0.f;
    #pragma unroll 4
    for (int e = 0; e < DD; ++e) {
        float v = Vs[e][nl];
        const float4* ar = (const float4*)&at4[e][dg*16];
        #pragma unroll
        for (int q = 0; q < 4; ++q) {
            float4 a = ar[q];
            acc[4*q+0] += a.x * v; acc[4*q+1] += a.y * v;
            acc[4*q+2] += a.z * v; acc[4*q+3] += a.w * v;
        }
    }
    const int n = n0 + nl;
    const int h = n >> 7, ww = n & 127;
    unsigned short* dst = AOT + (size_t)b*AOT_IMGE + (size_t)(h+1)*AOT_ROWE
                              + (size_t)(ww+1)*AOT_CI + dg*16;
    #pragma unroll
    for (int q = 0; q < 4; ++q) {
        ushort4 u;
        u.x = f2bf(acc[4*q+0]); u.y = f2bf(acc[4*q+1]);
        u.z = f2bf(acc[4*q+2]); u.w = f2bf(acc[4*q+3]);
        *(ushort4*)(dst + 4*q) = u;
    }
}

// ---------------------------------------------------------------------------
// K5: conv implicit-GEMM, 2 H-rows per block (unchanged).
// ---------------------------------------------------------------------------
__global__ __launch_bounds__(512, 1) void conv_kernel(
    const unsigned short* __restrict__ AOT, const unsigned short* __restrict__ Wt,
    const float* __restrict__ gammap, const float* __restrict__ x,
    float* __restrict__ out)
{
    __shared__ __align__(16) char lds[CONV_LDS];
    const int b   = blockIdx.y;
    const int h0  = blockIdx.x * 2;
    const int tid = threadIdx.x;
    const int wid = tid >> 6;
    const int lane = tid & 63;
    const int l15 = lane & 15;
    const int lj  = lane >> 4;
    const int wn  = wid & 1;
    const int wc  = wid >> 1;

    const char* psrc = (const char*)(AOT + (size_t)b*AOT_IMGE + (size_t)h0*AOT_ROWE);
    for (int i = tid; i < PATCH_SZ/16; i += 512)
        async_copy16(lds + i*16, psrc + i*16);
    for (int i = tid; i < WSLAB/16; i += 512)
        async_copy16(lds + PATCH_SZ + i*16, (const char*)Wt + i*16);
    __syncthreads();

    f32x4 acc[4][8];
    #pragma unroll
    for (int cf = 0; cf < 4; ++cf)
        #pragma unroll
        for (int nf = 0; nf < 8; ++nf)
            acc[cf][nf] = (f32x4){0.f, 0.f, 0.f, 0.f};

    for (int kk = 0; kk < 9; ++kk) {
        if (kk < 8) {
            const char* wsrc = (const char*)Wt + (size_t)(kk+1)*WSLAB;
            char* wdst = lds + PATCH_SZ + ((kk+1)&1)*WSLAB;
            for (int i = tid; i < WSLAB/16; i += 512)
                async_copy16(wdst + i*16, wsrc + i*16);
        }
        const int kh = kk / 3, kw = kk % 3;
        const char* wbase = lds + PATCH_SZ + (kk&1)*WSLAB;
        bf16x8 af[4];
        #pragma unroll
        for (int cf = 0; cf < 4; ++cf)
            af[cf] = ld_frag8(wbase + (wc*64 + cf*16 + l15)*88 + lj*16);
        #pragma unroll
        for (int nf = 0; nf < 8; ++nf) {
            const int cell = (wn + kh)*130 + nf*16 + l15 + kw;
            const bf16x8 bfr = ld_frag8(lds + cell*88 + lj*16);
            #pragma unroll
            for (int cf = 0; cf < 4; ++cf)
                acc[cf][nf] = __builtin_amdgcn_mfma_f32_16x16x32_bf16(
                    af[cf], bfr, acc[cf][nf], 0, 0, 0);
        }
        __syncthreads();
    }

    const float g0 = gammap[0];
    float* lf = (float*)lds;
    for (int k = 0; k < 4; ++k) {
        if (wc == k) {
            #pragma unroll
            for (int cf = 0; cf < 4; ++cf) {
                const int rl = cf*16 + 4*lj;
                #pragma unroll
                for (int nf = 0; nf < 8; ++nf) {
                    const int col = wn*128 + nf*16 + l15;
                    #pragma unroll
                    for (int j = 0; j < 4; ++j)
                        lf[(rl + j)*EPI_PITCH + col] = acc[cf][nf][j];
                }
            }
        }
        __syncthreads();
        #pragma unroll
        for (int it = 0; it < 8; ++it) {
            const int idx = tid + it*512;
            const int row = idx >> 6, c4 = idx & 63;
            const int co  = k*64 + row;
            const size_t g = ((size_t)b*CC + co)*NN + (size_t)h0*WW + c4*4;
            float4 v  = *(const float4*)(lf + row*EPI_PITCH + c4*4);
            float4 xv = *(const float4*)(x + g);
            float4 o;
            o.x = g0*gelu_fast(v.x) + xv.x;
            o.y = g0*gelu_fast(v.y) + xv.y;
            o.z = g0*gelu_fast(v.z) + xv.z;
            o.w = g0*gelu_fast(v.w) + xv.w;
            *(float4*)(out + g) = o;
        }
        __syncthreads();
    }
}

// ---------------------------------------------------------------------------
extern "C" void kernel_launch(void* const* d_in, const int* in_sizes, int n_in,
                              void* d_out, int out_size, void* d_ws, size_t ws_size,
                              hipStream_t stream)
{
    const float* x  = (const float*)d_in[0];
    const float* wq = (const float*)d_in[1];
    const float* bq = (const float*)d_in[2];
    const float* wk = (const float*)d_in[3];
    const float* bk = (const float*)d_in[4];
    const float* wv = (const float*)d_in[5];
    const float* bv = (const float*)d_in[6];
    const float* wp = (const float*)d_in[7];
    const float* gm = (const float*)d_in[8];
    float* out = (float*)d_out;

    // V scratch aliased into d_out (pv reads it before conv overwrites out).
    float* Vbuf = out;

    char* ws = (char*)d_ws;
    unsigned short* AOT  = (unsigned short*)ws;
    unsigned short* Wt   = (unsigned short*)(ws + AOT_ALLOC);
    unsigned short* Aswz = (unsigned short*)(ws + AOT_ALLOC + WT_BYTES);
    float* Ep  = (float*)(ws + AOT_ALLOC + WT_BYTES + ASWZ_BYTES);  // 1 MB
    float* ATT = Ep + (size_t)64*BB*1024;

    prep_kernel    <<<dim3(835), 256, 0, stream>>>(wp, Wt, wq, wk, wv, Aswz, AOT);
    qkv_mfma_kernel<<<dim3(64, BB), 512, 0, stream>>>(x, Aswz, bq, bk, bv, Vbuf, Ep);
    softmax_kernel <<<dim3(BB), dim3(32, 32), 0, stream>>>(Ep, ATT);
    pv_kernel      <<<dim3(128, BB), 256, 0, stream>>>(Vbuf, ATT, AOT);
    conv_kernel    <<<dim3(64, BB), 512, 0, stream>>>(AOT, Wt, gm, x, out);
}

// Round 15
// 75.514 us; speedup vs baseline: 2.1428x; 1.0578x over previous
//
#include <hip/hip_runtime.h>
#include <hip/hip_bf16.h>
#include <math.h>

#define BB 4
#define CC 256
#define HH 128
#define WW 128
#define NN (HH*WW)
#define DD 32

// AOT: attention output, bf16, spatially padded +1 border, ci padded 32->44.
#define AOT_CI   44
#define AOT_ROWE (130*AOT_CI)                  // shorts per padded row (5720)
#define AOT_IMGE (130*AOT_ROWE)                // shorts per batch (743600)
#define AOT_BYTES ((size_t)BB*AOT_IMGE*2)      // 5,948,800
#define AOT_ALLOC (AOT_BYTES + 1024)

#define WT_BYTES (9*256*AOT_CI*2)              // 202,752

// conv LDS geometry — 1-row tile for 2 blocks/CU (phase overlap)
#define PATCH1   34320                         // 3 padded rows * 130 * 88
#define WSLAB    22528                         // 256 co * 88
#define CONV_LDS1 (PATCH1 + 2*WSLAB)           // 79,376 -> 2 blocks/CU
#define EPI1_PITCH 132

// qkv: A image [16 kstep][hi/lo][3 cf][64 lane][16B] = 96 KB
#define ASWZ_BYTES 98304
#define QKVP 260                               // qk epilogue tile pitch (floats)
#define QKV_LDS 131584

typedef __attribute__((ext_vector_type(8)))  short bf16x8;
typedef __attribute__((ext_vector_type(4)))  float f32x4;
typedef __attribute__((ext_vector_type(16))) float f32x16;

__device__ inline void async_copy16(void* lds, const void* g) {
    __builtin_amdgcn_global_load_lds(
        (const __attribute__((address_space(1))) unsigned int*)g,
        (__attribute__((address_space(3))) unsigned int*)lds, 16, 0, 0);
}

__device__ inline unsigned short f2bf(float f) {
    __hip_bfloat16 h = __float2bfloat16(f);
    return *reinterpret_cast<unsigned short*>(&h);
}

__device__ inline void split2(float v, unsigned short& h, unsigned short& l) {
    __hip_bfloat16 hb = __float2bfloat16(v);
    float r = v - __bfloat162float(hb);     // exact (Sterbenz)
    __hip_bfloat16 lb = __float2bfloat16(r);
    h = *reinterpret_cast<unsigned short*>(&hb);
    l = *reinterpret_cast<unsigned short*>(&lb);
}

// truncation split packed: low16 = bf16(hi), high16 = bf16(lo residual)
__device__ inline unsigned int packsplit(float v) {
    unsigned int fb = __float_as_uint(v);
    unsigned int hb = fb & 0xFFFF0000u;
    float r = v - __uint_as_float(hb);
    unsigned int lb = __float_as_uint(r) >> 16;
    return (hb >> 16) | (lb << 16);
}

// 8B+8B LDS load of a bf16x8 fragment (88B row pitch is only 8B-aligned)
__device__ inline bf16x8 ld_frag8(const char* p) {
    union { bf16x8 v; short4 h[2]; } u;
    u.h[0] = *(const short4*)(p);
    u.h[1] = *(const short4*)(p + 8);
    return u.v;
}

// A&S 7.1.26 erf approximation, |err| ~1e-6
__device__ inline float gelu_fast(float v) {
    float a = fabsf(v) * 0.70710678118654752f;
    float t = __fdividef(1.0f, fmaf(0.3275911f, a, 1.0f));
    float p = t * fmaf(t, fmaf(t, fmaf(t, fmaf(t, 1.061405429f, -1.453152027f),
                                       1.421413741f), -0.284496736f), 0.254829592f);
    float e = 1.0f - p * __expf(-a * a);
    float erfv = (v < 0.0f) ? -e : e;
    return 0.5f * v * (1.0f + erfv);
}

// ---------------------------------------------------------------------------
// K0: fused prep — conv weight repack | qkv A-pack | AOT border zero.
// ---------------------------------------------------------------------------
__global__ __launch_bounds__(256) void prep_kernel(
    const float* __restrict__ wp, unsigned short* __restrict__ Wt,
    const float* __restrict__ wq, const float* __restrict__ wk,
    const float* __restrict__ wv, unsigned short* __restrict__ Aswz,
    unsigned short* __restrict__ AOT)
{
    const int blk = blockIdx.x;
    if (blk < 288) {                       // conv weights: 9*256*32 = 73728
        int i = blk*256 + threadIdx.x;
        int kk = i / (256*32);
        int r  = i % (256*32);
        int co = r >> 5, ci = r & 31;
        float v = wp[((size_t)co*32 + ci)*9 + kk];
        Wt[((size_t)kk*256 + co)*AOT_CI + ci] = f2bf(v);
    } else if (blk < 480) {                // qkv A image: 49152 entries
        int i = (blk-288)*256 + threadIdx.x;
        int j    = i & 7;
        int lane = (i >> 3) & 63;
        int q9   = i >> 9;                 // (s*2+hl)*3 + cf, 0..95
        int cf   = q9 % 3;
        int t    = q9 / 3;
        int hl   = t & 1;
        int s    = t >> 1;                 // 0..15
        int row  = cf*32 + (lane & 31);
        int c    = s*16 + (lane >> 5)*8 + j;
        float w  = (row < 32) ? wq[row*256 + c]
                 : (row < 64) ? wk[(row-32)*256 + c]
                              : wv[(row-64)*256 + c];
        unsigned short h, l;
        split2(w, h, l);
        Aswz[i] = hl ? l : h;
    } else {                               // AOT border zero: 4*22704 shorts
        int idx = (blk-480)*256 + threadIdx.x;
        if (idx < BB*22704) {
            int b = idx / 22704;
            int r = idx % 22704;
            size_t off;
            if (r < 11440) {
                int row = (r < 5720) ? 0 : 129;
                int e   = (r < 5720) ? r : r - 5720;
                off = (size_t)b*AOT_IMGE + (size_t)row*AOT_ROWE + e;
            } else {
                int r2 = r - 11440;
                int rr = r2 / 88 + 1;
                int w2 = r2 % 88;
                int col = (w2 < 44) ? 0 : 129;
                int ci  = (w2 < 44) ? w2 : w2 - 44;
                off = (size_t)b*AOT_IMGE + (size_t)rr*AOT_ROWE
                    + (size_t)col*AOT_CI + ci;
            }
            AOT[off] = 0;
        }
    }
}

// ---------------------------------------------------------------------------
// K1: QKV MFMA GEMM v7 (unchanged from r14 — barrier-free wave-private stage).
// ---------------------------------------------------------------------------
__global__ __launch_bounds__(512, 1) void qkv_mfma_kernel(
    const float* __restrict__ x, const unsigned short* __restrict__ Aswz,
    const float* __restrict__ bq, const float* __restrict__ bk,
    const float* __restrict__ bv,
    float* __restrict__ Vout, float* __restrict__ Ep)
{
    __shared__ __align__(16) char lds[QKV_LDS];
    const int b    = blockIdx.y;
    const int s    = blockIdx.x;                 // 0..63
    const int n0   = s * 256;
    const int tid  = threadIdx.x;
    const int w    = tid >> 6;
    const int lane = tid & 63;
    const int l31  = lane & 31;
    const int lh   = lane >> 5;
    const int chl  = lane >> 3;                  // 0..7 loader channel
    const int nq   = lane & 7;                   // loader n-quad

    for (int i = tid; i < 6144; i += 512)
        async_copy16(lds + i*16, (const char*)Aswz + i*16);
    float* biasL = (float*)(lds + 131072);
    if (tid < 96)
        biasL[tid] = (tid < 32) ? bq[tid] : (tid < 64) ? bk[tid-32] : bv[tid-64];

    char* mybuf = lds + 98304 + w*4096;          // wave-private 2 x 2KB
    const float* xq4 = x + (size_t)b*CC*NN + n0 + 32*w + nq*4;

    f32x16 acc0 = {0}, acc1 = {0}, acc2 = {0};

    float4 sa0, sb0, sa1, sb1, sa2, sb2;
    #define LOADX(VA, VB, R) do { \
        VA = *(const float4*)(xq4 + (size_t)((R)*16 + chl    )*NN); \
        VB = *(const float4*)(xq4 + (size_t)((R)*16 + 8 + chl)*NN); } while (0)
    #define PACKW(R, VA, VB) do { \
        unsigned int* bp = (unsigned int*)(mybuf + ((R) & 1)*2048); \
        uint4 ua, ub; \
        ua.x = packsplit((VA).x); ua.y = packsplit((VA).y); \
        ua.z = packsplit((VA).z); ua.w = packsplit((VA).w); \
        ub.x = packsplit((VB).x); ub.y = packsplit((VB).y); \
        ub.z = packsplit((VB).z); ub.w = packsplit((VB).w); \
        *(uint4*)(bp + (chl    )*32 + nq*4) = ua; \
        *(uint4*)(bp + (8 + chl)*32 + nq*4) = ub; } while (0)

    LOADX(sa0, sb0, 0);
    LOADX(sa1, sb1, 1);
    LOADX(sa2, sb2, 2);
    PACKW(0, sa0, sb0);
    __syncthreads();                             // A image resident

    #pragma unroll
    for (int r = 0; r < 16; ++r) {
        if (r + 3 < 16) {
            if ((r+3) % 3 == 0)      LOADX(sa0, sb0, r+3);
            else if ((r+3) % 3 == 1) LOADX(sa1, sb1, r+3);
            else                     LOADX(sa2, sb2, r+3);
        }
        {
            const unsigned int* bufc = (const unsigned int*)(mybuf + (r & 1)*2048);
            unsigned int u[8];
            #pragma unroll
            for (int j = 0; j < 8; ++j)
                u[j] = bufc[(lh*8 + j)*32 + l31];
            union { bf16x8 v; unsigned int d[4]; } B1, B2;
            #pragma unroll
            for (int dq = 0; dq < 4; ++dq) {
                B1.d[dq] = (u[2*dq] & 0xFFFFu) | (u[2*dq+1] << 16);
                B2.d[dq] = (u[2*dq] >> 16)     | (u[2*dq+1] & 0xFFFF0000u);
            }
            #pragma unroll
            for (int cf = 0; cf < 3; ++cf) {
                bf16x8 ah = *(const bf16x8*)(lds + (((r*6 +     cf)*64) + lane)*16);
                bf16x8 al = *(const bf16x8*)(lds + (((r*6 + 3 + cf)*64) + lane)*16);
                f32x16* ac = (cf == 0) ? &acc0 : (cf == 1) ? &acc1 : &acc2;
                *ac = __builtin_amdgcn_mfma_f32_32x32x16_bf16(ah, B1.v, *ac, 0, 0, 0);
                *ac = __builtin_amdgcn_mfma_f32_32x32x16_bf16(ah, B2.v, *ac, 0, 0, 0);
                *ac = __builtin_amdgcn_mfma_f32_32x32x16_bf16(al, B1.v, *ac, 0, 0, 0);
                *ac = __builtin_amdgcn_mfma_f32_32x32x16_bf16(al, B2.v, *ac, 0, 0, 0);
            }
        }
        if (r + 1 < 16) {
            if ((r+1) % 3 == 0)      PACKW(r+1, sa0, sb0);
            else if ((r+1) % 3 == 1) PACKW(r+1, sa1, sb1);
            else                     PACKW(r+1, sa2, sb2);
        }
    }
    #undef LOADX
    #undef PACKW

    __syncthreads();
    float* qk = (float*)lds;
    #pragma unroll
    for (int r = 0; r < 16; ++r) {
        const int rsub = (r & 3) + 8*(r >> 2) + 4*lh;
        const int col  = 32*w + l31;
        qk[rsub*QKVP + col]      = acc0[r] + biasL[rsub];
        qk[(32+rsub)*QKVP + col] = acc1[r] + biasL[32 + rsub];
        Vout[((size_t)b*DD + rsub)*NN + n0 + col] = acc2[r] + biasL[64 + rsub];
    }
    __syncthreads();

    const int d  = tid >> 4;                     // 0..31
    const int e2 = tid & 15;
    const float* qrow = qk + d*QKVP;
    float s0 = 0.f, s1 = 0.f;
    for (int n4 = 0; n4 < 256; n4 += 4) {
        float4 qv = *(const float4*)(qrow + n4);
        float4 ka = *(const float4*)(qk + (32 + e2)*QKVP + n4);
        float4 kb = *(const float4*)(qk + (48 + e2)*QKVP + n4);
        s0 += qv.x*ka.x + qv.y*ka.y + qv.z*ka.z + qv.w*ka.w;
        s1 += qv.x*kb.x + qv.y*kb.y + qv.z*kb.z + qv.w*kb.w;
    }
    float* ep = Ep + ((size_t)s*BB + b)*1024;
    ep[d*32 + e2]      = s0;
    ep[d*32 + e2 + 16] = s1;
}

// ---------------------------------------------------------------------------
// K4: PV with FUSED softmax.  grid (64 n-tiles of 256, B), 256 thr.
// Each block redundantly reduces Ep (64 partials, float4 L2 reads) and
// softmaxes (width-8 shuffles) -> at4[e][d] in LDS; then thread = one n,
// 32 d accums; writes bf16 AOT padded layout.  Deletes softmax kernel+ATT.
// ---------------------------------------------------------------------------
__global__ __launch_bounds__(256) void pv_kernel(
    const float* __restrict__ V, const float* __restrict__ Ep,
    unsigned short* __restrict__ AOT)
{
    __shared__ float Vs[DD][256];        // 32 KB
    __shared__ float at4[DD][DD];        // [e][d]
    const int b  = blockIdx.y;
    const int n0 = blockIdx.x * 256;
    const int tid = threadIdx.x;
    for (int i = tid; i < 2048; i += 256) {
        int r = i >> 6, c4 = i & 63;
        *(float4*)&Vs[r][c4*4] =
            *(const float4*)(V + ((size_t)b*DD + r)*NN + n0 + c4*4);
    }
    // fused softmax: thread -> (d = tid>>3, e = 4*(tid&7) .. +3)
    {
        const int d  = tid >> 3;
        const int eb = (tid & 7) * 4;
        float4 sum = {0.f, 0.f, 0.f, 0.f};
        #pragma unroll 8
        for (int p = 0; p < 64; ++p) {
            float4 v = *(const float4*)(Ep + ((size_t)p*BB + b)*1024 + d*32 + eb);
            sum.x += v.x; sum.y += v.y; sum.z += v.z; sum.w += v.w;
        }
        float nv0 = -sum.x, nv1 = -sum.y, nv2 = -sum.z, nv3 = -sum.w;
        float m = fmaxf(fmaxf(nv0, nv1), fmaxf(nv2, nv3));
        m = fmaxf(m, __shfl_xor(m, 4, 8));
        m = fmaxf(m, __shfl_xor(m, 2, 8));
        m = fmaxf(m, __shfl_xor(m, 1, 8));
        float p0 = expf(nv0 - m), p1 = expf(nv1 - m);
        float p2 = expf(nv2 - m), p3 = expf(nv3 - m);
        float su = p0 + p1 + p2 + p3;
        su += __shfl_xor(su, 4, 8);
        su += __shfl_xor(su, 2, 8);
        su += __shfl_xor(su, 1, 8);
        const float inv = 1.0f / su;
        at4[eb + 0][d] = p0 * inv;
        at4[eb + 1][d] = p1 * inv;
        at4[eb + 2][d] = p2 * inv;
        at4[eb + 3][d] = p3 * inv;
    }
    __syncthreads();

    const int t = tid;
    float acc[DD];
    #pragma unroll
    for (int k = 0; k < DD; ++k) acc[k] = 0.f;
    #pragma unroll 4
    for (int e = 0; e < DD; ++e) {
        float v = Vs[e][t];
        const float4* ar = (const float4*)at4[e];
        #pragma unroll
        for (int dq = 0; dq < 8; ++dq) {
            float4 a = ar[dq];
            acc[4*dq+0] += a.x * v; acc[4*dq+1] += a.y * v;
            acc[4*dq+2] += a.z * v; acc[4*dq+3] += a.w * v;
        }
    }
    const int n = n0 + t;
    const int h = n >> 7, ww = n & 127;
    unsigned short* dst = AOT + (size_t)b*AOT_IMGE + (size_t)(h+1)*AOT_ROWE
                              + (size_t)(ww+1)*AOT_CI;
    #pragma unroll
    for (int q = 0; q < 8; ++q) {
        ushort4 u;
        u.x = f2bf(acc[4*q+0]); u.y = f2bf(acc[4*q+1]);
        u.z = f2bf(acc[4*q+2]); u.w = f2bf(acc[4*q+3]);
        *(ushort4*)(dst + 4*q) = u;
    }
}

// ---------------------------------------------------------------------------
// K5: conv implicit-GEMM, 1 H-row per block, 256 thr = 4 waves (wave = 64 co),
// LDS 79.4 KB -> 2 blocks/CU: one block's HBM epilogue overlaps the other's
// MFMA phase (the r5-r14 conv had grid==CUs, zero cross-phase overlap).
// ---------------------------------------------------------------------------
__global__ __launch_bounds__(256, 2) void conv_kernel(
    const unsigned short* __restrict__ AOT, const unsigned short* __restrict__ Wt,
    const float* __restrict__ gammap, const float* __restrict__ x,
    float* __restrict__ out)
{
    __shared__ __align__(16) char lds[CONV_LDS1];
    const int b   = blockIdx.y;
    const int h   = blockIdx.x;                  // output row
    const int tid = threadIdx.x;
    const int wid = tid >> 6;                    // wave = 64-co block
    const int lane = tid & 63;
    const int l15 = lane & 15;
    const int lj  = lane >> 4;

    // stage patch rows h..h+2 (padded coords), 34,320 B linear
    const char* psrc = (const char*)(AOT + (size_t)b*AOT_IMGE + (size_t)h*AOT_ROWE);
    for (int i = tid; i < PATCH1/16; i += 256)
        async_copy16(lds + i*16, psrc + i*16);
    for (int i = tid; i < WSLAB/16; i += 256)
        async_copy16(lds + PATCH1 + i*16, (const char*)Wt + i*16);
    __syncthreads();

    f32x4 acc[4][8];
    #pragma unroll
    for (int cf = 0; cf < 4; ++cf)
        #pragma unroll
        for (int nf = 0; nf < 8; ++nf)
            acc[cf][nf] = (f32x4){0.f, 0.f, 0.f, 0.f};

    for (int kk = 0; kk < 9; ++kk) {
        if (kk < 8) {
            const char* wsrc = (const char*)Wt + (size_t)(kk+1)*WSLAB;
            char* wdst = lds + PATCH1 + ((kk+1)&1)*WSLAB;
            for (int i = tid; i < WSLAB/16; i += 256)
                async_copy16(wdst + i*16, wsrc + i*16);
        }
        const int kh = kk / 3, kw = kk % 3;
        const char* wbase = lds + PATCH1 + (kk&1)*WSLAB;
        bf16x8 af[4];
        #pragma unroll
        for (int cf = 0; cf < 4; ++cf)
            af[cf] = ld_frag8(wbase + (wid*64 + cf*16 + l15)*88 + lj*16);
        #pragma unroll
        for (int nf = 0; nf < 8; ++nf) {
            const int cell = kh*130 + nf*16 + l15 + kw;
            const bf16x8 bfr = ld_frag8(lds + cell*88 + lj*16);
            #pragma unroll
            for (int cf = 0; cf < 4; ++cf)
                acc[cf][nf] = __builtin_amdgcn_mfma_f32_16x16x32_bf16(
                    af[cf], bfr, acc[cf][nf], 0, 0, 0);
        }
        __syncthreads();
    }

    // epilogue: 4 chunks of 64 co; LDS bounce -> coalesced float4 I/O
    const float g0 = gammap[0];
    float* lf = (float*)lds;
    for (int k = 0; k < 4; ++k) {
        if (wid == k) {
            #pragma unroll
            for (int cf = 0; cf < 4; ++cf) {
                const int rl = cf*16 + 4*lj;
                #pragma unroll
                for (int nf = 0; nf < 8; ++nf) {
                    const int col = nf*16 + l15;
                    #pragma unroll
                    for (int j = 0; j < 4; ++j)
                        lf[(rl + j)*EPI1_PITCH + col] = acc[cf][nf][j];
                }
            }
        }
        __syncthreads();
        #pragma unroll
        for (int it = 0; it < 8; ++it) {
            const int idx = tid + it*256;            // 0..2047
            const int row = idx >> 5, c4 = idx & 31;
            const int co  = k*64 + row;
            const size_t g = ((size_t)b*CC + co)*NN + (size_t)h*WW + c4*4;
            float4 v  = *(const float4*)(lf + row*EPI1_PITCH + c4*4);
            float4 xv = *(const float4*)(x + g);
            float4 o;
            o.x = g0*gelu_fast(v.x) + xv.x;
            o.y = g0*gelu_fast(v.y) + xv.y;
            o.z = g0*gelu_fast(v.z) + xv.z;
            o.w = g0*gelu_fast(v.w) + xv.w;
            *(float4*)(out + g) = o;
        }
        __syncthreads();
    }
}

// ---------------------------------------------------------------------------
extern "C" void kernel_launch(void* const* d_in, const int* in_sizes, int n_in,
                              void* d_out, int out_size, void* d_ws, size_t ws_size,
                              hipStream_t stream)
{
    const float* x  = (const float*)d_in[0];
    const float* wq = (const float*)d_in[1];
    const float* bq = (const float*)d_in[2];
    const float* wk = (const float*)d_in[3];
    const float* bk = (const float*)d_in[4];
    const float* wv = (const float*)d_in[5];
    const float* bv = (const float*)d_in[6];
    const float* wp = (const float*)d_in[7];
    const float* gm = (const float*)d_in[8];
    float* out = (float*)d_out;

    // V scratch aliased into d_out (pv reads it before conv overwrites out).
    float* Vbuf = out;

    char* ws = (char*)d_ws;
    unsigned short* AOT  = (unsigned short*)ws;
    unsigned short* Wt   = (unsigned short*)(ws + AOT_ALLOC);
    unsigned short* Aswz = (unsigned short*)(ws + AOT_ALLOC + WT_BYTES);
    float* Ep  = (float*)(ws + AOT_ALLOC + WT_BYTES + ASWZ_BYTES);  // 1 MB

    prep_kernel    <<<dim3(835), 256, 0, stream>>>(wp, Wt, wq, wk, wv, Aswz, AOT);
    qkv_mfma_kernel<<<dim3(64, BB), 512, 0, stream>>>(x, Aswz, bq, bk, bv, Vbuf, Ep);
    pv_kernel      <<<dim3(64, BB), 256, 0, stream>>>(Vbuf, Ep, AOT);
    conv_kernel    <<<dim3(HH, BB), 256, 0, stream>>>(AOT, Wt, gm, x, out);
}